// Round 2
// baseline (430.904 us; speedup 1.0000x reference)
//
#include <hip/hip_runtime.h>
#include <math.h>

// Problem constants
#define B_  4
#define S_  1024
#define D_  1024
#define H_  16
#define DK_ 64
#define M_  (B_ * S_)   // 4096 rows for the big GEMMs

// ---------------------------------------------------------------------------
// GEMM: C[M,N] = A[M,K] @ W[K,N] + bias[N]   (fp32, row-major)
// BM=128, BN=64, BK=8, 256 threads, per-thread 8x4 micro-tile.
// ---------------------------------------------------------------------------
#define BM 128
#define BN 64
#define BK 8
#define TM 8
#define TN 4

__global__ __launch_bounds__(256) void gemm_bias(
    const float* __restrict__ A, const float* __restrict__ W,
    const float* __restrict__ bias, float* __restrict__ C,
    int M, int N, int K) {
  __shared__ float As[BK][BM];  // transposed A tile
  __shared__ float Bs[BK][BN];

  const int tid = threadIdx.x;
  const int m0 = blockIdx.y * BM;
  const int n0 = blockIdx.x * BN;

  // A tile load: 128 rows x 8 k = 1024 floats -> one float4 per thread
  const int rowA = tid >> 1;           // 0..127
  const int colA = (tid & 1) * 4;      // 0 or 4
  // B tile load: 8 rows x 64 cols = 512 floats -> one float2 per thread
  const int rowB = tid >> 5;           // 0..7
  const int colB = (tid & 31) * 2;     // 0..62

  const int tRow = (tid >> 4) * TM;    // 0..120
  const int tCol = (tid & 15) * TN;    // 0..60

  const float* Aptr = A + (size_t)(m0 + rowA) * K + colA;
  const float* Wptr = W + (size_t)rowB * N + n0 + colB;

  float acc[TM][TN] = {};

  for (int k0 = 0; k0 < K; k0 += BK) {
    const float4 a4 = *(const float4*)(Aptr + k0);
    const float2 b2 = *(const float2*)(Wptr + (size_t)k0 * N);

    __syncthreads();  // previous compute done before overwriting LDS
    As[colA + 0][rowA] = a4.x;
    As[colA + 1][rowA] = a4.y;
    As[colA + 2][rowA] = a4.z;
    As[colA + 3][rowA] = a4.w;
    *(float2*)&Bs[rowB][colB] = b2;
    __syncthreads();

#pragma unroll
    for (int kk = 0; kk < BK; ++kk) {
      float ra[TM], rb[TN];
      *(float4*)(ra + 0) = *(const float4*)&As[kk][tRow + 0];
      *(float4*)(ra + 4) = *(const float4*)&As[kk][tRow + 4];
      *(float4*)(rb + 0) = *(const float4*)&Bs[kk][tCol + 0];
#pragma unroll
      for (int i = 0; i < TM; ++i)
#pragma unroll
        for (int j = 0; j < TN; ++j)
          acc[i][j] = fmaf(ra[i], rb[j], acc[i][j]);
    }
  }

  const float4 bv = *(const float4*)(bias + n0 + tCol);
#pragma unroll
  for (int i = 0; i < TM; ++i) {
    float4 o;
    o.x = acc[i][0] + bv.x;
    o.y = acc[i][1] + bv.y;
    o.z = acc[i][2] + bv.z;
    o.w = acc[i][3] + bv.w;
    *(float4*)(C + (size_t)(m0 + tRow + i) * N + n0 + tCol) = o;
  }
}

// ---------------------------------------------------------------------------
// q0[b, n] = g[b, 0, :] @ Wq[:, n] + bq[n]      (only query position 0 needed)
// grid (D/64, B), 256 threads; split-K by 4 within the block.
// ---------------------------------------------------------------------------
__global__ __launch_bounds__(256) void q0_kernel(
    const float* __restrict__ g, const float* __restrict__ Wq,
    const float* __restrict__ bq, float* __restrict__ q0) {
  const int b = blockIdx.y;
  const int nsub = threadIdx.x & 63;
  const int n = blockIdx.x * 64 + nsub;
  const int ks = (threadIdx.x >> 6) * 256;

  const float* grow = g + (size_t)b * S_ * D_;  // row (b, s=0)
  float acc = 0.f;
  for (int k = ks; k < ks + 256; ++k)
    acc = fmaf(grow[k], Wq[(size_t)k * D_ + n], acc);

  __shared__ float red[256];
  red[threadIdx.x] = acc;
  __syncthreads();
  if (threadIdx.x < 64) {
    float v = red[threadIdx.x] + red[threadIdx.x + 64] +
              red[threadIdx.x + 128] + red[threadIdx.x + 192];
    q0[(size_t)b * D_ + n] = v + bq[n];
  }
}

// ---------------------------------------------------------------------------
// Attention row 0:
//   score[b,h,s] = (q0[b,h,:] . RoPE(k[b,h,s,:])) / 8, masked, softmax over s.
// RoPE(k): kw[2j]   = k[2j]*cos_j - k[2j+1]*sin_j
//          kw[2j+1] = k[2j+1]*cos_j + k[2j]*sin_j,  ang_j = s * 10000^(-j/32)
// One block per (b,h); 256 threads; each thread handles 4 s values.
// ---------------------------------------------------------------------------
__global__ __launch_bounds__(256) void attn_row0_kernel(
    const float* __restrict__ kproj, const float* __restrict__ q0,
    const int* __restrict__ mask, float* __restrict__ row0) {
  const int b = blockIdx.x >> 4;
  const int h = blockIdx.x & 15;
  const int tid = threadIdx.x;

  __shared__ float q0s[DK_];
  __shared__ float invs[32];
  __shared__ float wredm[4];
  __shared__ float wreds[4];

  if (tid < DK_) q0s[tid] = q0[(size_t)b * D_ + h * DK_ + tid];
  if (tid < 32)
    invs[tid] = (float)exp(-(double)tid * (9.210340371976182736 / 32.0)); // 10000^(-t/32)
  __syncthreads();

  float sc[4];
#pragma unroll
  for (int i = 0; i < 4; ++i) {
    const int s = tid + i * 256;
    const float4* kr =
        (const float4*)(kproj + ((size_t)(b * S_ + s)) * D_ + h * DK_);
    float dot = 0.f;
#pragma unroll
    for (int j2 = 0; j2 < 16; ++j2) {
      const float4 kv = kr[j2];
      const float fs = (float)s;
      float c0, s0n, c1, s1n;
      sincosf(fs * invs[2 * j2], &s0n, &c0);
      sincosf(fs * invs[2 * j2 + 1], &s1n, &c1);
      const float kw0 = kv.x * c0 - kv.y * s0n;
      const float kw1 = kv.y * c0 + kv.x * s0n;
      const float kw2 = kv.z * c1 - kv.w * s1n;
      const float kw3 = kv.w * c1 + kv.z * s1n;
      dot += q0s[4 * j2 + 0] * kw0 + q0s[4 * j2 + 1] * kw1 +
             q0s[4 * j2 + 2] * kw2 + q0s[4 * j2 + 3] * kw3;
    }
    dot *= 0.125f;  // 1/sqrt(64)
    if (mask[b * S_ + s] == 0) dot = -1e9f;
    sc[i] = dot;
  }

  // block max
  float mx = fmaxf(fmaxf(sc[0], sc[1]), fmaxf(sc[2], sc[3]));
#pragma unroll
  for (int off = 32; off > 0; off >>= 1) mx = fmaxf(mx, __shfl_xor(mx, off));
  if ((tid & 63) == 0) wredm[tid >> 6] = mx;
  __syncthreads();
  mx = fmaxf(fmaxf(wredm[0], wredm[1]), fmaxf(wredm[2], wredm[3]));

  float e[4];
  float sum = 0.f;
#pragma unroll
  for (int i = 0; i < 4; ++i) {
    e[i] = expf(sc[i] - mx);
    sum += e[i];
  }
#pragma unroll
  for (int off = 32; off > 0; off >>= 1) sum += __shfl_xor(sum, off);
  if ((tid & 63) == 0) wreds[tid >> 6] = sum;
  __syncthreads();
  sum = wreds[0] + wreds[1] + wreds[2] + wreds[3];

#pragma unroll
  for (int i = 0; i < 4; ++i)
    row0[((size_t)(b * H_ + h)) * S_ + tid + i * 256] = e[i] / sum;
}

// ---------------------------------------------------------------------------
// Conv1d (NCH, I=16, O=1024, k=3, pad=1) + bias + ReLU over row0 (B,16,S).
// out[b,o,s] = relu(cb[o] + sum_c sum_t row0[b,c,s+t-1] * cw[o,c,t])
// grid (S/16, B); 256 threads; thread = (o_group = tid>>4, s_lane = tid&15).
// ---------------------------------------------------------------------------
__global__ __launch_bounds__(256) void conv_relu_kernel(
    const float* __restrict__ row0, const float* __restrict__ cw,
    const float* __restrict__ cb, float* __restrict__ out) {
  const int b = blockIdx.y;
  const int s0 = blockIdx.x * 16;
  const int tid = threadIdx.x;

  __shared__ float sm[16][18];  // [c][s0-1 .. s0+16]
  // 16*18 = 288 elements > 256 threads: MUST loop (round-1 bug: `if (tid<288)`
  // left 32 elements uninitialized -> absmax 0.21).
  for (int i = tid; i < 16 * 18; i += 256) {
    const int c = i / 18, ss = i % 18;
    const int gs = s0 - 1 + ss;
    sm[c][ss] =
        (gs >= 0 && gs < S_) ? row0[((size_t)b * H_ + c) * S_ + gs] : 0.f;
  }
  __syncthreads();

  const int og = tid >> 4;   // 0..15
  const int si = tid & 15;   // 0..15

  float r[16][3];
#pragma unroll
  for (int c = 0; c < 16; ++c) {
    r[c][0] = sm[c][si + 0];
    r[c][1] = sm[c][si + 1];
    r[c][2] = sm[c][si + 2];
  }

  for (int o = og; o < D_; o += 16) {
    const float4* wo = (const float4*)(cw + (size_t)o * 48);
    float accv = cb[o];
#pragma unroll
    for (int q = 0; q < 12; ++q) {
      const float4 w4 = wo[q];
      const int f0 = q * 4;
      accv = fmaf(r[(f0 + 0) / 3][(f0 + 0) % 3], w4.x, accv);
      accv = fmaf(r[(f0 + 1) / 3][(f0 + 1) % 3], w4.y, accv);
      accv = fmaf(r[(f0 + 2) / 3][(f0 + 2) % 3], w4.z, accv);
      accv = fmaf(r[(f0 + 3) / 3][(f0 + 3) % 3], w4.w, accv);
    }
    out[((size_t)b * D_ + o) * S_ + s0 + si] = fmaxf(accv, 0.f);
  }
}

// ---------------------------------------------------------------------------
extern "C" void kernel_launch(void* const* d_in, const int* in_sizes, int n_in,
                              void* d_out, int out_size, void* d_ws,
                              size_t ws_size, hipStream_t stream) {
  const float* x    = (const float*)d_in[0];  // (B,S,D)
  const int*   mask = (const int*)d_in[1];    // (B,S)
  const float* W_G  = (const float*)d_in[2];
  const float* b_G  = (const float*)d_in[3];
  const float* Wq   = (const float*)d_in[4];
  const float* bq   = (const float*)d_in[5];
  const float* Wk   = (const float*)d_in[6];
  const float* bk   = (const float*)d_in[7];
  const float* cw   = (const float*)d_in[8];  // (D,H,3)
  const float* cb   = (const float*)d_in[9];
  float* out = (float*)d_out;                 // (B,D,S)

  char* ws = (char*)d_ws;
  float* g     = (float*)ws;                               // 16 MiB
  float* kproj = (float*)(ws + (16u << 20));               // 16 MiB
  float* q0    = (float*)(ws + (32u << 20));               // 16 KiB
  float* row0  = (float*)(ws + (32u << 20) + (1u << 16));  // 256 KiB

  const dim3 ggrid(D_ / BN, M_ / BM);  // (16, 32)
  gemm_bias<<<ggrid, 256, 0, stream>>>(x, W_G, b_G, g, M_, D_, D_);
  gemm_bias<<<ggrid, 256, 0, stream>>>(g, Wk, bk, kproj, M_, D_, D_);
  q0_kernel<<<dim3(D_ / 64, B_), 256, 0, stream>>>(g, Wq, bq, q0);
  attn_row0_kernel<<<B_ * H_, 256, 0, stream>>>(kproj, q0, mask, row0);
  conv_relu_kernel<<<dim3(S_ / 16, B_), 256, 0, stream>>>(row0, cw, cb, out);
}

// Round 3
// 324.803 us; speedup vs baseline: 1.3267x; 1.3267x over previous
//
#include <hip/hip_runtime.h>
#include <math.h>

// Problem constants
#define B_  4
#define S_  1024
#define D_  1024
#define H_  16
#define DK_ 64
#define M_  (B_ * S_)   // 4096 rows for the big GEMMs

typedef __bf16 bf16x8 __attribute__((ext_vector_type(8)));
typedef float  f32x4  __attribute__((ext_vector_type(4)));

// ---- bf16 helpers (RNE split) ---------------------------------------------
__device__ __forceinline__ unsigned short f2bf(float f) {
  unsigned u = __builtin_bit_cast(unsigned, f);
  u = (u + 0x7FFFu + ((u >> 16) & 1u)) >> 16;
  return (unsigned short)u;
}
__device__ __forceinline__ float bf2f(unsigned short h) {
  unsigned u = ((unsigned)h) << 16;
  return __builtin_bit_cast(float, u);
}

// async global->LDS, 16 B per lane; LDS dest = wave-uniform base + lane*16
__device__ __forceinline__ void gl_lds16(const void* g, void* lds) {
  __builtin_amdgcn_global_load_lds(
      (const __attribute__((address_space(1))) unsigned int*)(unsigned long long)g,
      (__attribute__((address_space(3))) unsigned int*)(unsigned int)(unsigned long long)lds,
      16, 0, 0);
}

// ---------------------------------------------------------------------------
// Split x (fp32) -> hi/lo bf16, elementwise. 4M elements, float4 per thread.
// ---------------------------------------------------------------------------
__global__ __launch_bounds__(256) void split_x_kernel(
    const float* __restrict__ X, unsigned short* __restrict__ hi,
    unsigned short* __restrict__ lo) {
  const int i = blockIdx.x * 256 + threadIdx.x;
  const float4 v = ((const float4*)X)[i];
  ushort4 h, l;
  h.x = f2bf(v.x); l.x = f2bf(v.x - bf2f(h.x));
  h.y = f2bf(v.y); l.y = f2bf(v.y - bf2f(h.y));
  h.z = f2bf(v.z); l.z = f2bf(v.z - bf2f(h.z));
  h.w = f2bf(v.w); l.w = f2bf(v.w - bf2f(h.w));
  ((ushort4*)hi)[i] = h;
  ((ushort4*)lo)[i] = l;
}

// ---------------------------------------------------------------------------
// Split + transpose W [K=1024][N=1024] fp32 -> WT hi/lo bf16 [N][K].
// 32x32 LDS tiles, grid (32,32), 256 threads (32x8).
// ---------------------------------------------------------------------------
__global__ __launch_bounds__(256) void split_wT_kernel(
    const float* __restrict__ W, unsigned short* __restrict__ hiT,
    unsigned short* __restrict__ loT) {
  __shared__ float t[32][33];
  const int k0 = blockIdx.x * 32;
  const int n0 = blockIdx.y * 32;
  const int tx = threadIdx.x & 31;
  const int ty = threadIdx.x >> 5;  // 0..7
#pragma unroll
  for (int r = 0; r < 32; r += 8)
    t[ty + r][tx] = W[(size_t)(k0 + ty + r) * 1024 + n0 + tx];
  __syncthreads();
#pragma unroll
  for (int r = 0; r < 32; r += 8) {
    const float v = t[tx][ty + r];  // = W[k0+tx][n0+ty+r]
    const unsigned short h = f2bf(v);
    const size_t idx = (size_t)(n0 + ty + r) * 1024 + k0 + tx;
    hiT[idx] = h;
    loT[idx] = f2bf(v - bf2f(h));
  }
}

// ---------------------------------------------------------------------------
// Split-precision bf16 MFMA GEMM (m97-ladder structure):
//   C = Ahi@Bhi + Ahi@Blo + Alo@Bhi  (+ bias)  ==  A@B to ~2^-16 rel.
// A*  : [4096][1024] bf16 row-major.  B*T : [1024][1024] bf16 row-major (B^T).
// Block tile 64(M)x128(N), BK=32, 256 thr = 4 waves side-by-side in N.
// Wave: 4x2 tiles of mfma_f32_16x16x32_bf16. grid (8,64) = 512 blocks.
// mode 0: fp32 out; mode 1: bf16 hi/lo split out (feeds next GEMM's A).
// ---------------------------------------------------------------------------
#define GM 64
#define GN 128
#define GKT 32

__global__ __launch_bounds__(256) void gemm3_mfma(
    const unsigned short* __restrict__ Ahi, const unsigned short* __restrict__ Alo,
    const unsigned short* __restrict__ BhiT, const unsigned short* __restrict__ BloT,
    const float* __restrict__ bias,
    float* __restrict__ Cf, unsigned short* __restrict__ Chi,
    unsigned short* __restrict__ Clo, int mode) {
  __shared__ __align__(16) unsigned short As[GM * GKT];   // 4 KB
  __shared__ __align__(16) unsigned short Bs[GN * GKT];   // 8 KB

  const int tid  = threadIdx.x;
  const int wv   = tid >> 6;
  const int lane = tid & 63;
  const int m0 = blockIdx.y * GM;
  const int n0 = blockIdx.x * GN;

  // staging: lane i of wave w loads 16 B; LDS lands at base + lane*16,
  // i.e. row = lane>>2 (32 bf16 = 64 B rows), col = (lane&3)*8.
  const int colOff = (lane & 3) * 8;
  const size_t aOff  = (size_t)(m0 + 16 * wv + (lane >> 2)) * 1024 + colOff;
  const size_t bOff0 = (size_t)(n0 + 32 * wv + (lane >> 2)) * 1024 + colOff;
  const size_t bOff1 = bOff0 + (size_t)16 * 1024;

  unsigned short* aDst  = As + wv * 512;          // 16 rows per wave
  unsigned short* bDst0 = Bs + wv * 1024;         // 32 rows per wave
  unsigned short* bDst1 = Bs + wv * 1024 + 512;

  const int l15  = lane & 15;
  const int quad = lane >> 4;

  f32x4 acc[4][2];
#pragma unroll
  for (int i = 0; i < 4; ++i)
#pragma unroll
    for (int j = 0; j < 2; ++j) acc[i][j] = (f32x4){0.f, 0.f, 0.f, 0.f};

#pragma unroll 1
  for (int seg = 0; seg < 3; ++seg) {
    const unsigned short* Ap = (seg == 2) ? Alo : Ahi;
    const unsigned short* Bp = (seg == 1) ? BloT : BhiT;
#pragma unroll 1
    for (int k0 = 0; k0 < 1024; k0 += GKT) {
      __syncthreads();                      // prior reads done before overwrite
      gl_lds16(Ap + aOff + k0, aDst);
      gl_lds16(Bp + bOff0 + k0, bDst0);
      gl_lds16(Bp + bOff1 + k0, bDst1);
      __syncthreads();                      // drains vmcnt (LDS writes visible)

      bf16x8 af[4], bfr[2];
#pragma unroll
      for (int mi = 0; mi < 4; ++mi)
        af[mi] = *(const bf16x8*)(As + (mi * 16 + l15) * GKT + quad * 8);
#pragma unroll
      for (int ni = 0; ni < 2; ++ni)
        bfr[ni] = *(const bf16x8*)(Bs + (wv * 32 + ni * 16 + l15) * GKT + quad * 8);
#pragma unroll
      for (int mi = 0; mi < 4; ++mi)
#pragma unroll
        for (int ni = 0; ni < 2; ++ni)
          acc[mi][ni] = __builtin_amdgcn_mfma_f32_16x16x32_bf16(
              af[mi], bfr[ni], acc[mi][ni], 0, 0, 0);
    }
  }

  // epilogue: C/D layout col = lane&15, row = quad*4 + r  [m89/m91 verified]
#pragma unroll
  for (int ni = 0; ni < 2; ++ni) {
    const int n = n0 + wv * 32 + ni * 16 + l15;
    const float bv = bias[n];
#pragma unroll
    for (int mi = 0; mi < 4; ++mi) {
#pragma unroll
      for (int r = 0; r < 4; ++r) {
        const int m = m0 + mi * 16 + quad * 4 + r;
        const float v = acc[mi][ni][r] + bv;
        const size_t idx = (size_t)m * 1024 + n;
        if (mode == 0) {
          Cf[idx] = v;
        } else {
          const unsigned short h = f2bf(v);
          Chi[idx] = h;
          Clo[idx] = f2bf(v - bf2f(h));
        }
      }
    }
  }
}

// ---------------------------------------------------------------------------
// q0[b, n] = g[b, 0, :] @ Wq[:, n] + bq[n]  (g reconstructed from hi+lo bf16)
// ---------------------------------------------------------------------------
__global__ __launch_bounds__(256) void q0_kernel(
    const unsigned short* __restrict__ Ghi, const unsigned short* __restrict__ Glo,
    const float* __restrict__ Wq, const float* __restrict__ bq,
    float* __restrict__ q0) {
  const int b = blockIdx.y;
  const int nsub = threadIdx.x & 63;
  const int n = blockIdx.x * 64 + nsub;
  const int ks = (threadIdx.x >> 6) * 256;

  const unsigned short* gh = Ghi + (size_t)b * S_ * D_;  // row (b, s=0)
  const unsigned short* gl = Glo + (size_t)b * S_ * D_;
  float acc = 0.f;
  for (int k = ks; k < ks + 256; ++k) {
    const float gv = bf2f(gh[k]) + bf2f(gl[k]);
    acc = fmaf(gv, Wq[(size_t)k * D_ + n], acc);
  }

  __shared__ float red[256];
  red[threadIdx.x] = acc;
  __syncthreads();
  if (threadIdx.x < 64) {
    float v = red[threadIdx.x] + red[threadIdx.x + 64] +
              red[threadIdx.x + 128] + red[threadIdx.x + 192];
    q0[(size_t)b * D_ + n] = v + bq[n];
  }
}

// ---------------------------------------------------------------------------
// Attention row 0 (unchanged from round 2, fp32 kproj input).
// ---------------------------------------------------------------------------
__global__ __launch_bounds__(256) void attn_row0_kernel(
    const float* __restrict__ kproj, const float* __restrict__ q0,
    const int* __restrict__ mask, float* __restrict__ row0) {
  const int b = blockIdx.x >> 4;
  const int h = blockIdx.x & 15;
  const int tid = threadIdx.x;

  __shared__ float q0s[DK_];
  __shared__ float invs[32];
  __shared__ float wredm[4];
  __shared__ float wreds[4];

  if (tid < DK_) q0s[tid] = q0[(size_t)b * D_ + h * DK_ + tid];
  if (tid < 32)
    invs[tid] = (float)exp(-(double)tid * (9.210340371976182736 / 32.0));
  __syncthreads();

  float sc[4];
#pragma unroll
  for (int i = 0; i < 4; ++i) {
    const int s = tid + i * 256;
    const float4* kr =
        (const float4*)(kproj + ((size_t)(b * S_ + s)) * D_ + h * DK_);
    float dot = 0.f;
#pragma unroll
    for (int j2 = 0; j2 < 16; ++j2) {
      const float4 kv = kr[j2];
      const float fs = (float)s;
      float c0, s0n, c1, s1n;
      sincosf(fs * invs[2 * j2], &s0n, &c0);
      sincosf(fs * invs[2 * j2 + 1], &s1n, &c1);
      const float kw0 = kv.x * c0 - kv.y * s0n;
      const float kw1 = kv.y * c0 + kv.x * s0n;
      const float kw2 = kv.z * c1 - kv.w * s1n;
      const float kw3 = kv.w * c1 + kv.z * s1n;
      dot += q0s[4 * j2 + 0] * kw0 + q0s[4 * j2 + 1] * kw1 +
             q0s[4 * j2 + 2] * kw2 + q0s[4 * j2 + 3] * kw3;
    }
    dot *= 0.125f;
    if (mask[b * S_ + s] == 0) dot = -1e9f;
    sc[i] = dot;
  }

  float mx = fmaxf(fmaxf(sc[0], sc[1]), fmaxf(sc[2], sc[3]));
#pragma unroll
  for (int off = 32; off > 0; off >>= 1) mx = fmaxf(mx, __shfl_xor(mx, off));
  if ((tid & 63) == 0) wredm[tid >> 6] = mx;
  __syncthreads();
  mx = fmaxf(fmaxf(wredm[0], wredm[1]), fmaxf(wredm[2], wredm[3]));

  float e[4];
  float sum = 0.f;
#pragma unroll
  for (int i = 0; i < 4; ++i) {
    e[i] = expf(sc[i] - mx);
    sum += e[i];
  }
#pragma unroll
  for (int off = 32; off > 0; off >>= 1) sum += __shfl_xor(sum, off);
  if ((tid & 63) == 0) wreds[tid >> 6] = sum;
  __syncthreads();
  sum = wreds[0] + wreds[1] + wreds[2] + wreds[3];

#pragma unroll
  for (int i = 0; i < 4; ++i)
    row0[((size_t)(b * H_ + h)) * S_ + tid + i * 256] = e[i] / sum;
}

// ---------------------------------------------------------------------------
// Conv1d (NCH, I=16, O=1024, k=3, pad=1) + bias + ReLU (unchanged, fixed loop)
// ---------------------------------------------------------------------------
__global__ __launch_bounds__(256) void conv_relu_kernel(
    const float* __restrict__ row0, const float* __restrict__ cw,
    const float* __restrict__ cb, float* __restrict__ out) {
  const int b = blockIdx.y;
  const int s0 = blockIdx.x * 16;
  const int tid = threadIdx.x;

  __shared__ float sm[16][18];
  for (int i = tid; i < 16 * 18; i += 256) {
    const int c = i / 18, ss = i % 18;
    const int gs = s0 - 1 + ss;
    sm[c][ss] =
        (gs >= 0 && gs < S_) ? row0[((size_t)b * H_ + c) * S_ + gs] : 0.f;
  }
  __syncthreads();

  const int og = tid >> 4;
  const int si = tid & 15;

  float r[16][3];
#pragma unroll
  for (int c = 0; c < 16; ++c) {
    r[c][0] = sm[c][si + 0];
    r[c][1] = sm[c][si + 1];
    r[c][2] = sm[c][si + 2];
  }

  for (int o = og; o < D_; o += 16) {
    const float4* wo = (const float4*)(cw + (size_t)o * 48);
    float accv = cb[o];
#pragma unroll
    for (int q = 0; q < 12; ++q) {
      const float4 w4 = wo[q];
      const int f0 = q * 4;
      accv = fmaf(r[(f0 + 0) / 3][(f0 + 0) % 3], w4.x, accv);
      accv = fmaf(r[(f0 + 1) / 3][(f0 + 1) % 3], w4.y, accv);
      accv = fmaf(r[(f0 + 2) / 3][(f0 + 2) % 3], w4.z, accv);
      accv = fmaf(r[(f0 + 3) / 3][(f0 + 3) % 3], w4.w, accv);
    }
    out[((size_t)b * D_ + o) * S_ + s0 + si] = fmaxf(accv, 0.f);
  }
}

// ---------------------------------------------------------------------------
// Workspace layout (peak 36.4 MB; round-2 proved >= 33.8 MB available):
//  [ 0, 8M)  Xhi            -> after GEMM1: kproj fp32 [0,16M)
//  [ 8,16M)  Xlo
//  [16,24M)  Ghi
//  [24,32M)  Glo
//  [32,34M)  W hiT   (W_G, then reused for Wk after GEMM1)
//  [34,36M)  W loT
//  [36M +64K) q0, [36M+64K, +320K) row0
// ---------------------------------------------------------------------------
extern "C" void kernel_launch(void* const* d_in, const int* in_sizes, int n_in,
                              void* d_out, int out_size, void* d_ws,
                              size_t ws_size, hipStream_t stream) {
  const float* x    = (const float*)d_in[0];
  const int*   mask = (const int*)d_in[1];
  const float* W_G  = (const float*)d_in[2];
  const float* b_G  = (const float*)d_in[3];
  const float* Wq   = (const float*)d_in[4];
  const float* bq   = (const float*)d_in[5];
  const float* Wk   = (const float*)d_in[6];
  const float* bk   = (const float*)d_in[7];
  const float* cw   = (const float*)d_in[8];
  const float* cb   = (const float*)d_in[9];
  float* out = (float*)d_out;

  char* ws = (char*)d_ws;
  unsigned short* Xhi  = (unsigned short*)(ws);
  unsigned short* Xlo  = (unsigned short*)(ws + (8u << 20));
  unsigned short* Ghi  = (unsigned short*)(ws + (16u << 20));
  unsigned short* Glo  = (unsigned short*)(ws + (24u << 20));
  unsigned short* WhiT = (unsigned short*)(ws + (32u << 20));
  unsigned short* WloT = (unsigned short*)(ws + (34u << 20));
  float* kproj = (float*)(ws);  // overwrites dead Xhi/Xlo after GEMM1
  float* q0    = (float*)(ws + (36u << 20));
  float* row0  = (float*)(ws + (36u << 20) + (1u << 16));

  split_x_kernel<<<M_ * D_ / 4 / 256, 256, 0, stream>>>(x, Xhi, Xlo);
  split_wT_kernel<<<dim3(32, 32), 256, 0, stream>>>(W_G, WhiT, WloT);
  gemm3_mfma<<<dim3(D_ / GN, M_ / GM), 256, 0, stream>>>(
      Xhi, Xlo, WhiT, WloT, b_G, nullptr, Ghi, Glo, 1);
  split_wT_kernel<<<dim3(32, 32), 256, 0, stream>>>(Wk, WhiT, WloT);
  gemm3_mfma<<<dim3(D_ / GN, M_ / GM), 256, 0, stream>>>(
      Ghi, Glo, WhiT, WloT, bk, kproj, nullptr, nullptr, 0);
  q0_kernel<<<dim3(D_ / 64, B_), 256, 0, stream>>>(Ghi, Glo, Wq, bq, q0);
  attn_row0_kernel<<<B_ * H_, 256, 0, stream>>>(kproj, q0, mask, row0);
  conv_relu_kernel<<<dim3(S_ / 16, B_), 256, 0, stream>>>(row0, cw, cb, out);
}

// Round 4
// 269.914 us; speedup vs baseline: 1.5964x; 1.2034x over previous
//
#include <hip/hip_runtime.h>
#include <math.h>

// Problem constants
#define B_  4
#define S_  1024
#define D_  1024
#define H_  16
#define DK_ 64
#define M_  (B_ * S_)   // 4096 rows for the big GEMMs

typedef __bf16 bf16x8 __attribute__((ext_vector_type(8)));
typedef float  f32x4  __attribute__((ext_vector_type(4)));

// ---- bf16 helpers (RNE split) ---------------------------------------------
__device__ __forceinline__ unsigned short f2bf(float f) {
  unsigned u = __builtin_bit_cast(unsigned, f);
  u = (u + 0x7FFFu + ((u >> 16) & 1u)) >> 16;
  return (unsigned short)u;
}
__device__ __forceinline__ float bf2f(unsigned short h) {
  unsigned u = ((unsigned)h) << 16;
  return __builtin_bit_cast(float, u);
}

// async global->LDS, 16 B per lane; LDS dest = wave-uniform base + lane*16
__device__ __forceinline__ void gl_lds16(const void* g, void* lds) {
  __builtin_amdgcn_global_load_lds(
      (const __attribute__((address_space(1))) unsigned int*)(unsigned long long)g,
      (__attribute__((address_space(3))) unsigned int*)(unsigned int)(unsigned long long)lds,
      16, 0, 0);
}

// ---------------------------------------------------------------------------
// Split x (fp32) -> hi/lo bf16, elementwise. 4M elements, float4 per thread.
// ---------------------------------------------------------------------------
__global__ __launch_bounds__(256) void split_x_kernel(
    const float* __restrict__ X, unsigned short* __restrict__ hi,
    unsigned short* __restrict__ lo) {
  const int i = blockIdx.x * 256 + threadIdx.x;
  const float4 v = ((const float4*)X)[i];
  ushort4 h, l;
  h.x = f2bf(v.x); l.x = f2bf(v.x - bf2f(h.x));
  h.y = f2bf(v.y); l.y = f2bf(v.y - bf2f(h.y));
  h.z = f2bf(v.z); l.z = f2bf(v.z - bf2f(h.z));
  h.w = f2bf(v.w); l.w = f2bf(v.w - bf2f(h.w));
  ((ushort4*)hi)[i] = h;
  ((ushort4*)lo)[i] = l;
}

// ---------------------------------------------------------------------------
// Split + transpose W [K=1024][N=1024] fp32 -> WT hi/lo bf16 [N][K].
// ---------------------------------------------------------------------------
__global__ __launch_bounds__(256) void split_wT_kernel(
    const float* __restrict__ W, unsigned short* __restrict__ hiT,
    unsigned short* __restrict__ loT) {
  __shared__ float t[32][33];
  const int k0 = blockIdx.x * 32;
  const int n0 = blockIdx.y * 32;
  const int tx = threadIdx.x & 31;
  const int ty = threadIdx.x >> 5;  // 0..7
#pragma unroll
  for (int r = 0; r < 32; r += 8)
    t[ty + r][tx] = W[(size_t)(k0 + ty + r) * 1024 + n0 + tx];
  __syncthreads();
#pragma unroll
  for (int r = 0; r < 32; r += 8) {
    const float v = t[tx][ty + r];  // = W[k0+tx][n0+ty+r]
    const unsigned short h = f2bf(v);
    const size_t idx = (size_t)(n0 + ty + r) * 1024 + k0 + tx;
    hiT[idx] = h;
    loT[idx] = f2bf(v - bf2f(h));
  }
}

// ---------------------------------------------------------------------------
// Split-precision bf16 MFMA GEMM (m97-ladder structure):
//   C = Ahi@Bhi + Ahi@Blo + Alo@Bhi  (+ bias)  ==  A@B to ~2^-16 rel.
// Block tile 64(M)x128(N), BK=32, 256 thr = 4 waves side-by-side in N.
// ---------------------------------------------------------------------------
#define GM 64
#define GN 128
#define GKT 32

__global__ __launch_bounds__(256) void gemm3_mfma(
    const unsigned short* __restrict__ Ahi, const unsigned short* __restrict__ Alo,
    const unsigned short* __restrict__ BhiT, const unsigned short* __restrict__ BloT,
    const float* __restrict__ bias,
    float* __restrict__ Cf, unsigned short* __restrict__ Chi,
    unsigned short* __restrict__ Clo, int mode) {
  __shared__ __align__(16) unsigned short As[GM * GKT];   // 4 KB
  __shared__ __align__(16) unsigned short Bs[GN * GKT];   // 8 KB

  const int tid  = threadIdx.x;
  const int wv   = tid >> 6;
  const int lane = tid & 63;
  const int m0 = blockIdx.y * GM;
  const int n0 = blockIdx.x * GN;

  const int colOff = (lane & 3) * 8;
  const size_t aOff  = (size_t)(m0 + 16 * wv + (lane >> 2)) * 1024 + colOff;
  const size_t bOff0 = (size_t)(n0 + 32 * wv + (lane >> 2)) * 1024 + colOff;
  const size_t bOff1 = bOff0 + (size_t)16 * 1024;

  unsigned short* aDst  = As + wv * 512;          // 16 rows per wave
  unsigned short* bDst0 = Bs + wv * 1024;         // 32 rows per wave
  unsigned short* bDst1 = Bs + wv * 1024 + 512;

  const int l15  = lane & 15;
  const int quad = lane >> 4;

  f32x4 acc[4][2];
#pragma unroll
  for (int i = 0; i < 4; ++i)
#pragma unroll
    for (int j = 0; j < 2; ++j) acc[i][j] = (f32x4){0.f, 0.f, 0.f, 0.f};

#pragma unroll 1
  for (int seg = 0; seg < 3; ++seg) {
    const unsigned short* Ap = (seg == 2) ? Alo : Ahi;
    const unsigned short* Bp = (seg == 1) ? BloT : BhiT;
#pragma unroll 1
    for (int k0 = 0; k0 < 1024; k0 += GKT) {
      __syncthreads();
      gl_lds16(Ap + aOff + k0, aDst);
      gl_lds16(Bp + bOff0 + k0, bDst0);
      gl_lds16(Bp + bOff1 + k0, bDst1);
      __syncthreads();

      bf16x8 af[4], bfr[2];
#pragma unroll
      for (int mi = 0; mi < 4; ++mi)
        af[mi] = *(const bf16x8*)(As + (mi * 16 + l15) * GKT + quad * 8);
#pragma unroll
      for (int ni = 0; ni < 2; ++ni)
        bfr[ni] = *(const bf16x8*)(Bs + (wv * 32 + ni * 16 + l15) * GKT + quad * 8);
#pragma unroll
      for (int mi = 0; mi < 4; ++mi)
#pragma unroll
        for (int ni = 0; ni < 2; ++ni)
          acc[mi][ni] = __builtin_amdgcn_mfma_f32_16x16x32_bf16(
              af[mi], bfr[ni], acc[mi][ni], 0, 0, 0);
    }
  }

  // epilogue: C/D layout col = lane&15, row = quad*4 + r
#pragma unroll
  for (int ni = 0; ni < 2; ++ni) {
    const int n = n0 + wv * 32 + ni * 16 + l15;
    const float bv = bias[n];
#pragma unroll
    for (int mi = 0; mi < 4; ++mi) {
#pragma unroll
      for (int r = 0; r < 4; ++r) {
        const int m = m0 + mi * 16 + quad * 4 + r;
        const float v = acc[mi][ni][r] + bv;
        const size_t idx = (size_t)m * 1024 + n;
        if (mode == 0) {
          Cf[idx] = v;
        } else {
          const unsigned short h = f2bf(v);
          Chi[idx] = h;
          Clo[idx] = f2bf(v - bf2f(h));
        }
      }
    }
  }
}

// ---------------------------------------------------------------------------
// q0 split-K GEMV partials: part[(slab*4+b)*1024+n] = sum_{k in slab} g[b,0,k]*Wq[k,n]
// grid (4 n-tiles, 32 k-slabs of 32), 256 threads. Wq rows read coalesced,
// each element reused across all 4 batches. (Round-3 q0_kernel: 64 blocks,
// 4KB-strided Wq walk, 100 us latency-bound. This: ideal 4 MB streamed.)
// ---------------------------------------------------------------------------
__global__ __launch_bounds__(256) void q0_partial(
    const unsigned short* __restrict__ Ghi, const unsigned short* __restrict__ Glo,
    const float* __restrict__ Wq, float* __restrict__ part) {
  const int slab = blockIdx.y;                      // 0..31
  const int n = blockIdx.x * 256 + threadIdx.x;     // 0..1023

  __shared__ float gs[4][32];
  if (threadIdx.x < 128) {
    const int b = threadIdx.x >> 5, kk = threadIdx.x & 31;
    const size_t gi = (size_t)b * S_ * D_ + slab * 32 + kk;
    gs[b][kk] = bf2f(Ghi[gi]) + bf2f(Glo[gi]);
  }
  __syncthreads();

  float a0 = 0.f, a1 = 0.f, a2 = 0.f, a3 = 0.f;
#pragma unroll
  for (int kk = 0; kk < 32; ++kk) {
    const float w = Wq[(size_t)(slab * 32 + kk) * D_ + n];
    a0 = fmaf(gs[0][kk], w, a0);
    a1 = fmaf(gs[1][kk], w, a1);
    a2 = fmaf(gs[2][kk], w, a2);
    a3 = fmaf(gs[3][kk], w, a3);
  }
  part[(size_t)(slab * 4 + 0) * D_ + n] = a0;
  part[(size_t)(slab * 4 + 1) * D_ + n] = a1;
  part[(size_t)(slab * 4 + 2) * D_ + n] = a2;
  part[(size_t)(slab * 4 + 3) * D_ + n] = a3;
}

// ---------------------------------------------------------------------------
// RoPE table: tab[s*64 + 2j] = cos(s*inv_j), tab[s*64+2j+1] = sin(s*inv_j)
// grid 128, 256 threads -> 32768 (s,j) pairs.
// ---------------------------------------------------------------------------
__global__ __launch_bounds__(256) void rope_table_kernel(float* __restrict__ tab) {
  const int idx = blockIdx.x * 256 + threadIdx.x;
  const int s = idx >> 5, j = idx & 31;
  const float inv = (float)exp(-(double)j * (9.210340371976182736 / 32.0));
  float sn, c;
  sincosf((float)s * inv, &sn, &c);
  tab[(size_t)s * 64 + 2 * j] = c;
  tab[(size_t)s * 64 + 2 * j + 1] = sn;
}

// ---------------------------------------------------------------------------
// Attention row 0: reduce q0 partials (+bq), then per-s RoPE'd dot + softmax.
// One block per (b,h); 256 threads; each thread 4 s values. Table-driven RoPE.
// ---------------------------------------------------------------------------
__global__ __launch_bounds__(256) void attn_row0_kernel(
    const float* __restrict__ kproj, const float* __restrict__ part,
    const float* __restrict__ bq, const float* __restrict__ tab,
    const int* __restrict__ mask, float* __restrict__ row0) {
  const int b = blockIdx.x >> 4;
  const int h = blockIdx.x & 15;
  const int tid = threadIdx.x;

  __shared__ float q0s[DK_];
  __shared__ float wredm[4];
  __shared__ float wreds[4];

  if (tid < 64) {
    const int n = h * DK_ + tid;
    float v = bq[n];
#pragma unroll
    for (int sl = 0; sl < 32; ++sl) v += part[(size_t)(sl * 4 + b) * D_ + n];
    q0s[tid] = v;
  }
  __syncthreads();

  float sc[4];
#pragma unroll
  for (int i = 0; i < 4; ++i) {
    const int s = tid + i * 256;
    const float4* kr =
        (const float4*)(kproj + ((size_t)(b * S_ + s)) * D_ + h * DK_);
    const float4* tb = (const float4*)(tab + (size_t)s * 64);
    float dot = 0.f;
#pragma unroll
    for (int j2 = 0; j2 < 16; ++j2) {
      const float4 kv = kr[j2];
      const float4 cs = tb[j2];  // cos0, sin0, cos1, sin1
      const float kw0 = kv.x * cs.x - kv.y * cs.y;
      const float kw1 = kv.y * cs.x + kv.x * cs.y;
      const float kw2 = kv.z * cs.z - kv.w * cs.w;
      const float kw3 = kv.w * cs.z + kv.z * cs.w;
      dot += q0s[4 * j2 + 0] * kw0 + q0s[4 * j2 + 1] * kw1 +
             q0s[4 * j2 + 2] * kw2 + q0s[4 * j2 + 3] * kw3;
    }
    dot *= 0.125f;  // 1/sqrt(64)
    if (mask[b * S_ + s] == 0) dot = -1e9f;
    sc[i] = dot;
  }

  float mx = fmaxf(fmaxf(sc[0], sc[1]), fmaxf(sc[2], sc[3]));
#pragma unroll
  for (int off = 32; off > 0; off >>= 1) mx = fmaxf(mx, __shfl_xor(mx, off));
  if ((tid & 63) == 0) wredm[tid >> 6] = mx;
  __syncthreads();
  mx = fmaxf(fmaxf(wredm[0], wredm[1]), fmaxf(wredm[2], wredm[3]));

  float e[4];
  float sum = 0.f;
#pragma unroll
  for (int i = 0; i < 4; ++i) {
    e[i] = expf(sc[i] - mx);
    sum += e[i];
  }
#pragma unroll
  for (int off = 32; off > 0; off >>= 1) sum += __shfl_xor(sum, off);
  if ((tid & 63) == 0) wreds[tid >> 6] = sum;
  __syncthreads();
  sum = wreds[0] + wreds[1] + wreds[2] + wreds[3];

#pragma unroll
  for (int i = 0; i < 4; ++i)
    row0[((size_t)(b * H_ + h)) * S_ + tid + i * 256] = e[i] / sum;
}

// ---------------------------------------------------------------------------
// Conv1d (NCH, I=16, O=1024, k=3, pad=1) + bias + ReLU over row0 (B,16,S).
// ---------------------------------------------------------------------------
__global__ __launch_bounds__(256) void conv_relu_kernel(
    const float* __restrict__ row0, const float* __restrict__ cw,
    const float* __restrict__ cb, float* __restrict__ out) {
  const int b = blockIdx.y;
  const int s0 = blockIdx.x * 16;
  const int tid = threadIdx.x;

  __shared__ float sm[16][18];
  for (int i = tid; i < 16 * 18; i += 256) {
    const int c = i / 18, ss = i % 18;
    const int gs = s0 - 1 + ss;
    sm[c][ss] =
        (gs >= 0 && gs < S_) ? row0[((size_t)b * H_ + c) * S_ + gs] : 0.f;
  }
  __syncthreads();

  const int og = tid >> 4;
  const int si = tid & 15;

  float r[16][3];
#pragma unroll
  for (int c = 0; c < 16; ++c) {
    r[c][0] = sm[c][si + 0];
    r[c][1] = sm[c][si + 1];
    r[c][2] = sm[c][si + 2];
  }

  for (int o = og; o < D_; o += 16) {
    const float4* wo = (const float4*)(cw + (size_t)o * 48);
    float accv = cb[o];
#pragma unroll
    for (int q = 0; q < 12; ++q) {
      const float4 w4 = wo[q];
      const int f0 = q * 4;
      accv = fmaf(r[(f0 + 0) / 3][(f0 + 0) % 3], w4.x, accv);
      accv = fmaf(r[(f0 + 1) / 3][(f0 + 1) % 3], w4.y, accv);
      accv = fmaf(r[(f0 + 2) / 3][(f0 + 2) % 3], w4.z, accv);
      accv = fmaf(r[(f0 + 3) / 3][(f0 + 3) % 3], w4.w, accv);
    }
    out[((size_t)b * D_ + o) * S_ + s0 + si] = fmaxf(accv, 0.f);
  }
}

// ---------------------------------------------------------------------------
// Workspace (peak 36 MB):
//  [ 0, 8M)  Xhi   -> after GEMM1 dead; kproj fp32 takes [0,16M)
//  [ 8,16M)  Xlo
//  [16,24M)  Ghi
//  [24,32M)  Glo
//  [32,36M)  WhiT/WloT  -> dead after GEMM2; then q0part(512K)+table(256K)+row0(256K)
// ---------------------------------------------------------------------------
extern "C" void kernel_launch(void* const* d_in, const int* in_sizes, int n_in,
                              void* d_out, int out_size, void* d_ws,
                              size_t ws_size, hipStream_t stream) {
  const float* x    = (const float*)d_in[0];
  const int*   mask = (const int*)d_in[1];
  const float* W_G  = (const float*)d_in[2];
  const float* b_G  = (const float*)d_in[3];
  const float* Wq   = (const float*)d_in[4];
  const float* bq   = (const float*)d_in[5];
  const float* Wk   = (const float*)d_in[6];
  const float* bk   = (const float*)d_in[7];
  const float* cw   = (const float*)d_in[8];
  const float* cb   = (const float*)d_in[9];
  float* out = (float*)d_out;

  char* ws = (char*)d_ws;
  unsigned short* Xhi  = (unsigned short*)(ws);
  unsigned short* Xlo  = (unsigned short*)(ws + (8u << 20));
  unsigned short* Ghi  = (unsigned short*)(ws + (16u << 20));
  unsigned short* Glo  = (unsigned short*)(ws + (24u << 20));
  unsigned short* WhiT = (unsigned short*)(ws + (32u << 20));
  unsigned short* WloT = (unsigned short*)(ws + (34u << 20));
  float* kproj  = (float*)(ws);                               // after GEMM1
  float* q0part = (float*)(ws + (32u << 20));                 // after GEMM2
  float* ropeT  = (float*)(ws + (32u << 20) + (512u << 10));
  float* row0   = (float*)(ws + (32u << 20) + (768u << 10));

  split_x_kernel<<<M_ * D_ / 4 / 256, 256, 0, stream>>>(x, Xhi, Xlo);
  split_wT_kernel<<<dim3(32, 32), 256, 0, stream>>>(W_G, WhiT, WloT);
  gemm3_mfma<<<dim3(D_ / GN, M_ / GM), 256, 0, stream>>>(
      Xhi, Xlo, WhiT, WloT, b_G, nullptr, Ghi, Glo, 1);
  split_wT_kernel<<<dim3(32, 32), 256, 0, stream>>>(Wk, WhiT, WloT);
  gemm3_mfma<<<dim3(D_ / GN, M_ / GM), 256, 0, stream>>>(
      Ghi, Glo, WhiT, WloT, bk, kproj, nullptr, nullptr, 0);
  q0_partial<<<dim3(4, 32), 256, 0, stream>>>(Ghi, Glo, Wq, q0part);
  rope_table_kernel<<<128, 256, 0, stream>>>(ropeT);
  attn_row0_kernel<<<B_ * H_, 256, 0, stream>>>(kproj, q0part, bq, ropeT,
                                                mask, row0);
  conv_relu_kernel<<<dim3(S_ / 16, B_), 256, 0, stream>>>(row0, cw, cb, out);
}

// Round 5
// 213.939 us; speedup vs baseline: 2.0141x; 1.2616x over previous
//
#include <hip/hip_runtime.h>
#include <math.h>

// Problem constants
#define B_  4
#define S_  1024
#define D_  1024
#define H_  16
#define DK_ 64
#define M_  (B_ * S_)   // 4096 rows for the big GEMMs

typedef __bf16 bf16x8 __attribute__((ext_vector_type(8)));
typedef float  f32x4  __attribute__((ext_vector_type(4)));

// ---- bf16 helpers (RNE split) ---------------------------------------------
__device__ __forceinline__ unsigned short f2bf(float f) {
  unsigned u = __builtin_bit_cast(unsigned, f);
  u = (u + 0x7FFFu + ((u >> 16) & 1u)) >> 16;
  return (unsigned short)u;
}
__device__ __forceinline__ float bf2f(unsigned short h) {
  unsigned u = ((unsigned)h) << 16;
  return __builtin_bit_cast(float, u);
}

// async global->LDS, 16 B per lane; LDS dest = wave-uniform base + lane*16
__device__ __forceinline__ void gl_lds16(const void* g, void* lds) {
  __builtin_amdgcn_global_load_lds(
      (const __attribute__((address_space(1))) unsigned int*)(unsigned long long)g,
      (__attribute__((address_space(3))) unsigned int*)(unsigned int)(unsigned long long)lds,
      16, 0, 0);
}

// ---------------------------------------------------------------------------
// Split x (fp32) -> hi/lo bf16, elementwise. float4 per thread.
// ---------------------------------------------------------------------------
__global__ __launch_bounds__(256) void split_x_kernel(
    const float* __restrict__ X, unsigned short* __restrict__ hi,
    unsigned short* __restrict__ lo) {
  const int i = blockIdx.x * 256 + threadIdx.x;
  const float4 v = ((const float4*)X)[i];
  ushort4 h, l;
  h.x = f2bf(v.x); l.x = f2bf(v.x - bf2f(h.x));
  h.y = f2bf(v.y); l.y = f2bf(v.y - bf2f(h.y));
  h.z = f2bf(v.z); l.z = f2bf(v.z - bf2f(h.z));
  h.w = f2bf(v.w); l.w = f2bf(v.w - bf2f(h.w));
  ((ushort4*)hi)[i] = h;
  ((ushort4*)lo)[i] = l;
}

// ---------------------------------------------------------------------------
// Split + transpose W [K=1024][N=1024] fp32 -> WT hi/lo bf16 [N][K].
// ---------------------------------------------------------------------------
__global__ __launch_bounds__(256) void split_wT_kernel(
    const float* __restrict__ W, unsigned short* __restrict__ hiT,
    unsigned short* __restrict__ loT) {
  __shared__ float t[32][33];
  const int k0 = blockIdx.x * 32;
  const int n0 = blockIdx.y * 32;
  const int tx = threadIdx.x & 31;
  const int ty = threadIdx.x >> 5;  // 0..7
#pragma unroll
  for (int r = 0; r < 32; r += 8)
    t[ty + r][tx] = W[(size_t)(k0 + ty + r) * 1024 + n0 + tx];
  __syncthreads();
#pragma unroll
  for (int r = 0; r < 32; r += 8) {
    const float v = t[tx][ty + r];  // = W[k0+tx][n0+ty+r]
    const unsigned short h = f2bf(v);
    const size_t idx = (size_t)(n0 + ty + r) * 1024 + k0 + tx;
    hiT[idx] = h;
    loT[idx] = f2bf(v - bf2f(h));
  }
}

// ---------------------------------------------------------------------------
// FUSED split-precision bf16 MFMA GEMM:
//   C = Ahi@Bhi + Ahi@Blo + Alo@Bhi (+bias), all 3 products in ONE K-pass
//   chained into the same accumulator (mfma D=A*B+C). vs round 4's 3
//   sequential segments: 3x the MFMA per barrier pair (24 vs 8 per wave),
//   K-loop 32 iters vs 96 -> 3x fewer vmcnt(0)+barrier drains.
// Block tile 64(M)x128(N), BK=32, 256 thr = 4 waves side-by-side in N.
// grid (8, 64) = 512 blocks = 2/CU. LDS 24 KB.
// mode 0: fp32 out; mode 1: bf16 hi/lo split out (feeds next GEMM's A).
// ---------------------------------------------------------------------------
#define GM 64
#define GN 128
#define GKT 32

__global__ __launch_bounds__(256) void gemm3_fused(
    const unsigned short* __restrict__ Ahi, const unsigned short* __restrict__ Alo,
    const unsigned short* __restrict__ BhiT, const unsigned short* __restrict__ BloT,
    const float* __restrict__ bias,
    float* __restrict__ Cf, unsigned short* __restrict__ Chi,
    unsigned short* __restrict__ Clo, int mode) {
  __shared__ __align__(16) unsigned short AhS[GM * GKT];   // 4 KB
  __shared__ __align__(16) unsigned short AlS[GM * GKT];   // 4 KB
  __shared__ __align__(16) unsigned short BhS[GN * GKT];   // 8 KB
  __shared__ __align__(16) unsigned short BlS[GN * GKT];   // 8 KB

  const int tid  = threadIdx.x;
  const int wv   = tid >> 6;
  const int lane = tid & 63;
  const int m0 = blockIdx.y * GM;
  const int n0 = blockIdx.x * GN;

  // staging: lane i loads 16 B; LDS lands at base + lane*16,
  // i.e. row = lane>>2 (32 bf16 = 64 B rows), col = (lane&3)*8.
  const int colOff = (lane & 3) * 8;
  const size_t aOff  = (size_t)(m0 + 16 * wv + (lane >> 2)) * 1024 + colOff;
  const size_t bOff0 = (size_t)(n0 + 32 * wv + (lane >> 2)) * 1024 + colOff;
  const size_t bOff1 = bOff0 + (size_t)16 * 1024;

  unsigned short* ahDst  = AhS + wv * 512;          // 16 A rows per wave
  unsigned short* alDst  = AlS + wv * 512;
  unsigned short* bhDst0 = BhS + wv * 1024;         // 32 B rows per wave
  unsigned short* bhDst1 = BhS + wv * 1024 + 512;
  unsigned short* blDst0 = BlS + wv * 1024;
  unsigned short* blDst1 = BlS + wv * 1024 + 512;

  const int l15  = lane & 15;
  const int quad = lane >> 4;

  f32x4 acc[4][2];
#pragma unroll
  for (int i = 0; i < 4; ++i)
#pragma unroll
    for (int j = 0; j < 2; ++j) acc[i][j] = (f32x4){0.f, 0.f, 0.f, 0.f};

#pragma unroll 1
  for (int k0 = 0; k0 < 1024; k0 += GKT) {
    __syncthreads();                      // prior LDS reads done
    gl_lds16(Ahi  + aOff  + k0, ahDst);
    gl_lds16(Alo  + aOff  + k0, alDst);
    gl_lds16(BhiT + bOff0 + k0, bhDst0);
    gl_lds16(BhiT + bOff1 + k0, bhDst1);
    gl_lds16(BloT + bOff0 + k0, blDst0);
    gl_lds16(BloT + bOff1 + k0, blDst1);
    __syncthreads();                      // vmcnt drain: LDS writes visible

    bf16x8 ah[4], al[4], bh[2], bl[2];
#pragma unroll
    for (int mi = 0; mi < 4; ++mi) {
      ah[mi] = *(const bf16x8*)(AhS + (mi * 16 + l15) * GKT + quad * 8);
      al[mi] = *(const bf16x8*)(AlS + (mi * 16 + l15) * GKT + quad * 8);
    }
#pragma unroll
    for (int ni = 0; ni < 2; ++ni) {
      bh[ni] = *(const bf16x8*)(BhS + (wv * 32 + ni * 16 + l15) * GKT + quad * 8);
      bl[ni] = *(const bf16x8*)(BlS + (wv * 32 + ni * 16 + l15) * GKT + quad * 8);
    }
#pragma unroll
    for (int mi = 0; mi < 4; ++mi)
#pragma unroll
      for (int ni = 0; ni < 2; ++ni) {
        acc[mi][ni] = __builtin_amdgcn_mfma_f32_16x16x32_bf16(
            ah[mi], bh[ni], acc[mi][ni], 0, 0, 0);
        acc[mi][ni] = __builtin_amdgcn_mfma_f32_16x16x32_bf16(
            ah[mi], bl[ni], acc[mi][ni], 0, 0, 0);
        acc[mi][ni] = __builtin_amdgcn_mfma_f32_16x16x32_bf16(
            al[mi], bh[ni], acc[mi][ni], 0, 0, 0);
      }
  }

  // epilogue: C/D layout col = lane&15, row = quad*4 + r
#pragma unroll
  for (int ni = 0; ni < 2; ++ni) {
    const int n = n0 + wv * 32 + ni * 16 + l15;
    const float bv = bias[n];
#pragma unroll
    for (int mi = 0; mi < 4; ++mi) {
#pragma unroll
      for (int r = 0; r < 4; ++r) {
        const int m = m0 + mi * 16 + quad * 4 + r;
        const float v = acc[mi][ni][r] + bv;
        const size_t idx = (size_t)m * 1024 + n;
        if (mode == 0) {
          Cf[idx] = v;
        } else {
          const unsigned short h = f2bf(v);
          Chi[idx] = h;
          Clo[idx] = f2bf(v - bf2f(h));
        }
      }
    }
  }
}

// ---------------------------------------------------------------------------
// q0 split-K GEMV partials (coalesced Wq stream, reused across batches).
// ---------------------------------------------------------------------------
__global__ __launch_bounds__(256) void q0_partial(
    const unsigned short* __restrict__ Ghi, const unsigned short* __restrict__ Glo,
    const float* __restrict__ Wq, float* __restrict__ part) {
  const int slab = blockIdx.y;                      // 0..31
  const int n = blockIdx.x * 256 + threadIdx.x;     // 0..1023

  __shared__ float gs[4][32];
  if (threadIdx.x < 128) {
    const int b = threadIdx.x >> 5, kk = threadIdx.x & 31;
    const size_t gi = (size_t)b * S_ * D_ + slab * 32 + kk;
    gs[b][kk] = bf2f(Ghi[gi]) + bf2f(Glo[gi]);
  }
  __syncthreads();

  float a0 = 0.f, a1 = 0.f, a2 = 0.f, a3 = 0.f;
#pragma unroll
  for (int kk = 0; kk < 32; ++kk) {
    const float w = Wq[(size_t)(slab * 32 + kk) * D_ + n];
    a0 = fmaf(gs[0][kk], w, a0);
    a1 = fmaf(gs[1][kk], w, a1);
    a2 = fmaf(gs[2][kk], w, a2);
    a3 = fmaf(gs[3][kk], w, a3);
  }
  part[(size_t)(slab * 4 + 0) * D_ + n] = a0;
  part[(size_t)(slab * 4 + 1) * D_ + n] = a1;
  part[(size_t)(slab * 4 + 2) * D_ + n] = a2;
  part[(size_t)(slab * 4 + 3) * D_ + n] = a3;
}

// ---------------------------------------------------------------------------
// RoPE table: tab[s*64 + 2j] = cos(s*inv_j), tab[s*64+2j+1] = sin(s*inv_j)
// ---------------------------------------------------------------------------
__global__ __launch_bounds__(256) void rope_table_kernel(float* __restrict__ tab) {
  const int idx = blockIdx.x * 256 + threadIdx.x;
  const int s = idx >> 5, j = idx & 31;
  const float inv = (float)exp(-(double)j * (9.210340371976182736 / 32.0));
  float sn, c;
  sincosf((float)s * inv, &sn, &c);
  tab[(size_t)s * 64 + 2 * j] = c;
  tab[(size_t)s * 64 + 2 * j + 1] = sn;
}

// ---------------------------------------------------------------------------
// Phase 1 softmax: raw scores + per-chunk (max, sum-of-exp-rel-max).
// grid 256 = (b,h,chunk of 256 s), 256 threads, 1 s per thread.
// (Round-4 attn: 64 blocks latency-bound; now 4x parallelism, 1/4 work each.)
// ---------------------------------------------------------------------------
__global__ __launch_bounds__(256) void attn_scores_kernel(
    const float* __restrict__ kproj, const float* __restrict__ part,
    const float* __restrict__ bq, const float* __restrict__ tab,
    const int* __restrict__ mask, float* __restrict__ scores,
    float* __restrict__ mS) {
  const int b = blockIdx.x >> 6;
  const int h = (blockIdx.x >> 2) & 15;
  const int chunk = blockIdx.x & 3;
  const int tid = threadIdx.x;
  const int bh = b * H_ + h;
  const int s = chunk * 256 + tid;

  __shared__ float q0s[DK_];
  __shared__ float wred[4];

  if (tid < 64) {
    const int n = h * DK_ + tid;
    float v = bq[n];
#pragma unroll
    for (int sl = 0; sl < 32; ++sl) v += part[(size_t)(sl * 4 + b) * D_ + n];
    q0s[tid] = v;
  }
  __syncthreads();

  const float4* kr =
      (const float4*)(kproj + ((size_t)(b * S_ + s)) * D_ + h * DK_);
  const float4* tb = (const float4*)(tab + (size_t)s * 64);
  float dot = 0.f;
#pragma unroll
  for (int j2 = 0; j2 < 16; ++j2) {
    const float4 kv = kr[j2];
    const float4 cs = tb[j2];  // cos0, sin0, cos1, sin1
    const float kw0 = kv.x * cs.x - kv.y * cs.y;
    const float kw1 = kv.y * cs.x + kv.x * cs.y;
    const float kw2 = kv.z * cs.z - kv.w * cs.w;
    const float kw3 = kv.w * cs.z + kv.z * cs.w;
    dot += q0s[4 * j2 + 0] * kw0 + q0s[4 * j2 + 1] * kw1 +
           q0s[4 * j2 + 2] * kw2 + q0s[4 * j2 + 3] * kw3;
  }
  dot *= 0.125f;  // 1/sqrt(64)
  if (mask[b * S_ + s] == 0) dot = -1e9f;
  scores[(size_t)bh * S_ + s] = dot;

  // block max
  float mx = dot;
#pragma unroll
  for (int off = 32; off > 0; off >>= 1) mx = fmaxf(mx, __shfl_xor(mx, off));
  if ((tid & 63) == 0) wred[tid >> 6] = mx;
  __syncthreads();
  mx = fmaxf(fmaxf(wred[0], wred[1]), fmaxf(wred[2], wred[3]));
  __syncthreads();

  // block sum of exp(dot - mx)
  float e = expf(dot - mx);
#pragma unroll
  for (int off = 32; off > 0; off >>= 1) e += __shfl_xor(e, off);
  if ((tid & 63) == 0) wred[tid >> 6] = e;
  __syncthreads();
  if (tid == 0) {
    mS[(size_t)(bh * 4 + chunk) * 2 + 0] = mx;
    mS[(size_t)(bh * 4 + chunk) * 2 + 1] = wred[0] + wred[1] + wred[2] + wred[3];
  }
}

// ---------------------------------------------------------------------------
// Phase 2 softmax: combine 4 chunk partials per (b,h) -> (max, 1/sum).
// ---------------------------------------------------------------------------
__global__ __launch_bounds__(64) void softmax_combine_kernel(
    const float* __restrict__ mS, float* __restrict__ msum) {
  const int bh = threadIdx.x;  // 0..63
  float m = -3e38f;
#pragma unroll
  for (int c = 0; c < 4; ++c) m = fmaxf(m, mS[(size_t)(bh * 4 + c) * 2]);
  float S = 0.f;
#pragma unroll
  for (int c = 0; c < 4; ++c)
    S += mS[(size_t)(bh * 4 + c) * 2 + 1] * expf(mS[(size_t)(bh * 4 + c) * 2] - m);
  msum[bh * 2 + 0] = m;
  msum[bh * 2 + 1] = 1.f / S;
}

// ---------------------------------------------------------------------------
// Conv1d (NCH, I=16, O=1024, k=3, pad=1) + bias + ReLU; input is raw scores,
// normalized on the fly: p = exp(sc - m_bh) * invS_bh.
// grid (S/16=64, B, 4 o-quarters), 256 threads = (16 o-groups x 16 s).
// ---------------------------------------------------------------------------
__global__ __launch_bounds__(256) void conv_norm_relu_kernel(
    const float* __restrict__ scores, const float* __restrict__ msum,
    const float* __restrict__ cw, const float* __restrict__ cb,
    float* __restrict__ out) {
  const int b = blockIdx.y;
  const int s0 = blockIdx.x * 16;
  const int oz = blockIdx.z * 256;
  const int tid = threadIdx.x;

  __shared__ float sm[16][18];  // normalized p, [c][s0-1 .. s0+16]
  for (int i = tid; i < 16 * 18; i += 256) {
    const int c = i / 18, ss = i % 18;
    const int gs = s0 - 1 + ss;
    float p = 0.f;
    if (gs >= 0 && gs < S_) {
      const int bh = b * H_ + c;
      const float sc = scores[(size_t)bh * S_ + gs];
      p = expf(sc - msum[bh * 2]) * msum[bh * 2 + 1];
    }
    sm[c][ss] = p;
  }
  __syncthreads();

  const int og = tid >> 4;   // 0..15
  const int si = tid & 15;   // 0..15

  float r[16][3];
#pragma unroll
  for (int c = 0; c < 16; ++c) {
    r[c][0] = sm[c][si + 0];
    r[c][1] = sm[c][si + 1];
    r[c][2] = sm[c][si + 2];
  }

#pragma unroll 1
  for (int i = 0; i < 16; ++i) {
    const int o = oz + i * 16 + og;
    const float4* wo = (const float4*)(cw + (size_t)o * 48);
    float accv = cb[o];
#pragma unroll
    for (int q = 0; q < 12; ++q) {
      const float4 w4 = wo[q];
      const int f0 = q * 4;
      accv = fmaf(r[(f0 + 0) / 3][(f0 + 0) % 3], w4.x, accv);
      accv = fmaf(r[(f0 + 1) / 3][(f0 + 1) % 3], w4.y, accv);
      accv = fmaf(r[(f0 + 2) / 3][(f0 + 2) % 3], w4.z, accv);
      accv = fmaf(r[(f0 + 3) / 3][(f0 + 3) % 3], w4.w, accv);
    }
    out[((size_t)b * D_ + o) * S_ + s0 + si] = fmaxf(accv, 0.f);
  }
}

// ---------------------------------------------------------------------------
// Workspace (peak 36.4 MB, proven available in rounds 3-4):
//  [ 0, 8M)  Xhi   -> dead after GEMM1; kproj fp32 takes [0,16M)
//  [ 8,16M)  Xlo
//  [16,24M)  Ghi
//  [24,32M)  Glo
//  [32,36M)  WhiT/WloT (W_G, then Wk) -> dead after GEMM2, then:
//            q0part(512K) | ropeT(256K) | scores(256K) | mS(2K) | msum(0.5K)
// ---------------------------------------------------------------------------
extern "C" void kernel_launch(void* const* d_in, const int* in_sizes, int n_in,
                              void* d_out, int out_size, void* d_ws,
                              size_t ws_size, hipStream_t stream) {
  const float* x    = (const float*)d_in[0];
  const int*   mask = (const int*)d_in[1];
  const float* W_G  = (const float*)d_in[2];
  const float* b_G  = (const float*)d_in[3];
  const float* Wq   = (const float*)d_in[4];
  const float* bq   = (const float*)d_in[5];
  const float* Wk   = (const float*)d_in[6];
  const float* bk   = (const float*)d_in[7];
  const float* cw   = (const float*)d_in[8];
  const float* cb   = (const float*)d_in[9];
  float* out = (float*)d_out;

  char* ws = (char*)d_ws;
  unsigned short* Xhi  = (unsigned short*)(ws);
  unsigned short* Xlo  = (unsigned short*)(ws + (8u << 20));
  unsigned short* Ghi  = (unsigned short*)(ws + (16u << 20));
  unsigned short* Glo  = (unsigned short*)(ws + (24u << 20));
  unsigned short* WhiT = (unsigned short*)(ws + (32u << 20));
  unsigned short* WloT = (unsigned short*)(ws + (34u << 20));
  float* kproj  = (float*)(ws);                                  // after GEMM1
  float* q0part = (float*)(ws + (32u << 20));                    // after GEMM2
  float* ropeT  = (float*)(ws + (32u << 20) + (512u << 10));
  float* scores = (float*)(ws + (32u << 20) + (768u << 10));
  float* mS     = (float*)(ws + (32u << 20) + (1024u << 10));
  float* msum   = (float*)(ws + (32u << 20) + (1024u << 10) + 4096);

  split_x_kernel<<<M_ * D_ / 4 / 256, 256, 0, stream>>>(x, Xhi, Xlo);
  split_wT_kernel<<<dim3(32, 32), 256, 0, stream>>>(W_G, WhiT, WloT);
  gemm3_fused<<<dim3(D_ / GN, M_ / GM), 256, 0, stream>>>(
      Xhi, Xlo, WhiT, WloT, b_G, nullptr, Ghi, Glo, 1);
  split_wT_kernel<<<dim3(32, 32), 256, 0, stream>>>(Wk, WhiT, WloT);
  gemm3_fused<<<dim3(D_ / GN, M_ / GM), 256, 0, stream>>>(
      Ghi, Glo, WhiT, WloT, bk, kproj, nullptr, nullptr, 0);
  q0_partial<<<dim3(4, 32), 256, 0, stream>>>(Ghi, Glo, Wq, q0part);
  rope_table_kernel<<<128, 256, 0, stream>>>(ropeT);
  attn_scores_kernel<<<256, 256, 0, stream>>>(kproj, q0part, bq, ropeT, mask,
                                              scores, mS);
  softmax_combine_kernel<<<1, 64, 0, stream>>>(mS, msum);
  conv_norm_relu_kernel<<<dim3(S_ / 16, B_, 4), 256, 0, stream>>>(
      scores, msum, cw, cb, out);
}

// Round 6
// 163.220 us; speedup vs baseline: 2.6400x; 1.3107x over previous
//
#include <hip/hip_runtime.h>
#include <math.h>

// Problem constants
#define B_  4
#define S_  1024
#define D_  1024
#define H_  16
#define DK_ 64
#define M_  (B_ * S_)   // 4096 rows for the big GEMMs

typedef __bf16 bf16x8 __attribute__((ext_vector_type(8)));
typedef float  f32x4  __attribute__((ext_vector_type(4)));

// ---- bf16 helpers (RNE) ----------------------------------------------------
__device__ __forceinline__ unsigned short f2bf(float f) {
  unsigned u = __builtin_bit_cast(unsigned, f);
  u = (u + 0x7FFFu + ((u >> 16) & 1u)) >> 16;
  return (unsigned short)u;
}
__device__ __forceinline__ float bf2f(unsigned short h) {
  unsigned u = ((unsigned)h) << 16;
  return __builtin_bit_cast(float, u);
}

// async global->LDS, 16 B per lane; LDS dest = wave-uniform base + lane*16
__device__ __forceinline__ void gl_lds16(const void* g, void* lds) {
  __builtin_amdgcn_global_load_lds(
      (const __attribute__((address_space(1))) unsigned int*)(unsigned long long)g,
      (__attribute__((address_space(3))) unsigned int*)(unsigned int)(unsigned long long)lds,
      16, 0, 0);
}

// ---------------------------------------------------------------------------
// PREP (one kernel, branch by blockIdx -> fewer serialized launches):
//  blocks [0,2048):    X fp32 -> bf16 cast (8 elems/thread)
//  blocks [2048,3072): W_G transpose+cast -> WGT bf16 [n][k]
//  blocks [3072,4096): Wk  transpose+cast -> WkT bf16 [n][k]
//  blocks [4096,4224): RoPE table tab[s*64+2j]=cos(s*inv_j), +1 = sin
// ---------------------------------------------------------------------------
__global__ __launch_bounds__(256) void prep_kernel(
    const float* __restrict__ X, const float* __restrict__ W_G,
    const float* __restrict__ Wk, unsigned short* __restrict__ Xbf,
    unsigned short* __restrict__ WGT, unsigned short* __restrict__ WkT,
    float* __restrict__ tab) {
  __shared__ float tle[32][33];
  const int blk = blockIdx.x;
  const int tid = threadIdx.x;

  if (blk < 2048) {
    const int i = (blk * 256 + tid) * 2;  // float4 index
    const float4 v0 = ((const float4*)X)[i];
    const float4 v1 = ((const float4*)X)[i + 1];
    ushort4 h0, h1;
    h0.x = f2bf(v0.x); h0.y = f2bf(v0.y); h0.z = f2bf(v0.z); h0.w = f2bf(v0.w);
    h1.x = f2bf(v1.x); h1.y = f2bf(v1.y); h1.z = f2bf(v1.z); h1.w = f2bf(v1.w);
    ((ushort4*)Xbf)[i] = h0;
    ((ushort4*)Xbf)[i + 1] = h1;
  } else if (blk < 4096) {
    const bool isG = blk < 3072;
    const float* W = isG ? W_G : Wk;
    unsigned short* WT = isG ? WGT : WkT;
    const int t = isG ? blk - 2048 : blk - 3072;
    const int k0 = (t & 31) * 32;
    const int n0 = (t >> 5) * 32;
    const int tx = tid & 31;
    const int ty = tid >> 5;  // 0..7
#pragma unroll
    for (int r = 0; r < 32; r += 8)
      tle[ty + r][tx] = W[(size_t)(k0 + ty + r) * 1024 + n0 + tx];
    __syncthreads();
#pragma unroll
    for (int r = 0; r < 32; r += 8)
      WT[(size_t)(n0 + ty + r) * 1024 + k0 + tx] = f2bf(tle[tx][ty + r]);
  } else {
    const int idx = (blk - 4096) * 256 + tid;
    const int s = idx >> 5, j = idx & 31;
    const float inv = (float)exp(-(double)j * (9.210340371976182736 / 32.0));
    float sn, c;
    sincosf((float)s * inv, &sn, &c);
    tab[(size_t)s * 64 + 2 * j] = c;
    tab[(size_t)s * 64 + 2 * j + 1] = sn;
  }
}

// ---------------------------------------------------------------------------
// bf16 MFMA GEMM, C[M,N] = bf16(A@B + bias). A bf16 [4096][1024], BT bf16
// [N][K]. Tile 64(M)x128(N), BK=64 as two 32-halves (separate LDS buffers ->
// 64B rows stay glds16-compatible & 2-way-bank-free). 16 MFMA/wave/barrier,
// 16 K-iters (round 5: 32 iters). grid flat 1-D; blocks >= nGemmBlocks run
// the fused q0 split-K GEMV (A = G is this GEMM's own input).
// ---------------------------------------------------------------------------
#define GM 64
#define GN 128

__global__ __launch_bounds__(256) void gemm_bf16(
    const unsigned short* __restrict__ A, const unsigned short* __restrict__ BT,
    const float* __restrict__ bias, unsigned short* __restrict__ C,
    const float* __restrict__ Wq, float* __restrict__ part, int nGemmBlocks) {
  __shared__ __align__(16) unsigned short As[2][GM * 32];   // 8 KB
  __shared__ __align__(16) unsigned short Bs[2][GN * 32];   // 16 KB
  __shared__ float gs[4][32];

  const int flat = blockIdx.x;
  const int tid  = threadIdx.x;

  if (flat >= nGemmBlocks) {
    // ---- fused q0 partial: part[(slab*4+b)*D+n] = sum_k g[b,0,k]*Wq[k,n]
    const int qb = flat - nGemmBlocks;   // 0..127
    const int slab = qb >> 2;            // 0..31
    const int n = (qb & 3) * 256 + tid;  // 0..1023
    if (tid < 128) {
      const int b = tid >> 5, kk = tid & 31;
      gs[b][kk] = bf2f(A[(size_t)b * S_ * D_ + slab * 32 + kk]);
    }
    __syncthreads();
    float a0 = 0.f, a1 = 0.f, a2 = 0.f, a3 = 0.f;
#pragma unroll
    for (int kk = 0; kk < 32; ++kk) {
      const float w = Wq[(size_t)(slab * 32 + kk) * D_ + n];
      a0 = fmaf(gs[0][kk], w, a0);
      a1 = fmaf(gs[1][kk], w, a1);
      a2 = fmaf(gs[2][kk], w, a2);
      a3 = fmaf(gs[3][kk], w, a3);
    }
    part[(size_t)(slab * 4 + 0) * D_ + n] = a0;
    part[(size_t)(slab * 4 + 1) * D_ + n] = a1;
    part[(size_t)(slab * 4 + 2) * D_ + n] = a2;
    part[(size_t)(slab * 4 + 3) * D_ + n] = a3;
    return;
  }

  // ---- GEMM path
  const int bx = flat & 7;        // N tiles: 1024/128 = 8
  const int by = flat >> 3;       // M tiles: 4096/64 = 64
  const int wv   = tid >> 6;
  const int lane = tid & 63;
  const int m0 = by * GM;
  const int n0 = bx * GN;

  // staging: 16 rows x 64B per glds; row = lane>>2, col = (lane&3)*8 elems
  const int colOff = (lane & 3) * 8;
  const size_t aOff  = (size_t)(m0 + 16 * wv + (lane >> 2)) * 1024 + colOff;
  const size_t bOff0 = (size_t)(n0 + 32 * wv + (lane >> 2)) * 1024 + colOff;
  const size_t bOff1 = bOff0 + (size_t)16 * 1024;

  const int l15  = lane & 15;
  const int quad = lane >> 4;

  f32x4 acc[4][2];
#pragma unroll
  for (int i = 0; i < 4; ++i)
#pragma unroll
    for (int j = 0; j < 2; ++j) acc[i][j] = (f32x4){0.f, 0.f, 0.f, 0.f};

#pragma unroll 1
  for (int k0 = 0; k0 < 1024; k0 += 64) {
    __syncthreads();                      // prior LDS reads done
#pragma unroll
    for (int ks = 0; ks < 2; ++ks) {
      gl_lds16(A  + aOff  + k0 + ks * 32, &As[ks][wv * 512]);
      gl_lds16(BT + bOff0 + k0 + ks * 32, &Bs[ks][wv * 1024]);
      gl_lds16(BT + bOff1 + k0 + ks * 32, &Bs[ks][wv * 1024 + 512]);
    }
    __syncthreads();                      // vmcnt drain: LDS writes visible

#pragma unroll
    for (int ks = 0; ks < 2; ++ks) {
      bf16x8 af[4], bfr[2];
#pragma unroll
      for (int mi = 0; mi < 4; ++mi)
        af[mi] = *(const bf16x8*)(&As[ks][(mi * 16 + l15) * 32 + quad * 8]);
#pragma unroll
      for (int ni = 0; ni < 2; ++ni)
        bfr[ni] =
            *(const bf16x8*)(&Bs[ks][(wv * 32 + ni * 16 + l15) * 32 + quad * 8]);
#pragma unroll
      for (int mi = 0; mi < 4; ++mi)
#pragma unroll
        for (int ni = 0; ni < 2; ++ni)
          acc[mi][ni] = __builtin_amdgcn_mfma_f32_16x16x32_bf16(
              af[mi], bfr[ni], acc[mi][ni], 0, 0, 0);
    }
  }

  // epilogue: C/D layout col = lane&15, row = quad*4 + r (m89/m91 verified)
#pragma unroll
  for (int ni = 0; ni < 2; ++ni) {
    const int n = n0 + wv * 32 + ni * 16 + l15;
    const float bv = bias[n];
#pragma unroll
    for (int mi = 0; mi < 4; ++mi) {
#pragma unroll
      for (int r = 0; r < 4; ++r) {
        const int m = m0 + mi * 16 + quad * 4 + r;
        C[(size_t)m * 1024 + n] = f2bf(acc[mi][ni][r] + bv);
      }
    }
  }
}

// ---------------------------------------------------------------------------
// Attention row-0 scores, coalesced: 8 lanes share one s-row (each lane loads
// a contiguous 16B chunk of k -> 128B coalesced per group), butterfly-reduce
// the dot over width 8. Block = (b,h,chunk of 32 s); grid 2048.
// Writes raw score + per-chunk (max, expsum) for deferred normalization.
// ---------------------------------------------------------------------------
__global__ __launch_bounds__(256) void attn_scores_kernel(
    const unsigned short* __restrict__ Kbf, const float* __restrict__ part,
    const float* __restrict__ bq, const float* __restrict__ tab,
    const int* __restrict__ mask, float* __restrict__ scores,
    float* __restrict__ mS) {
  const int bi = blockIdx.x;
  const int b = bi >> 9;
  const int h = (bi >> 5) & 15;
  const int chunk = bi & 31;
  const int tid = threadIdx.x;
  const int bh = b * H_ + h;
  const int sl = tid >> 3;  // 0..31
  const int j  = tid & 7;   // 16B chunk within the 64-elem row
  const int s  = chunk * 32 + sl;

  __shared__ float q0s[DK_];
  __shared__ float wredm[4];
  __shared__ float wreds[4];

  if (tid < 64) {
    const int n = h * DK_ + tid;
    float v = bq[n];
#pragma unroll
    for (int sl2 = 0; sl2 < 32; ++sl2)
      v += part[(size_t)(sl2 * 4 + b) * D_ + n];
    q0s[tid] = v;
  }
  __syncthreads();

  const ushort4* kp =
      (const ushort4*)(Kbf + ((size_t)(b * S_ + s)) * D_ + h * DK_ + j * 8);
  const ushort4 k0 = kp[0], k1 = kp[1];
  const float4* tb = (const float4*)(tab + (size_t)s * 64 + j * 8);
  const float4 t0 = tb[0], t1 = tb[1];

  float dot = 0.f;
  {
    const float ka = bf2f(k0.x), kb = bf2f(k0.y);
    dot += q0s[j * 8 + 0] * (ka * t0.x - kb * t0.y) +
           q0s[j * 8 + 1] * (kb * t0.x + ka * t0.y);
  }
  {
    const float ka = bf2f(k0.z), kb = bf2f(k0.w);
    dot += q0s[j * 8 + 2] * (ka * t0.z - kb * t0.w) +
           q0s[j * 8 + 3] * (kb * t0.z + ka * t0.w);
  }
  {
    const float ka = bf2f(k1.x), kb = bf2f(k1.y);
    dot += q0s[j * 8 + 4] * (ka * t1.x - kb * t1.y) +
           q0s[j * 8 + 5] * (kb * t1.x + ka * t1.y);
  }
  {
    const float ka = bf2f(k1.z), kb = bf2f(k1.w);
    dot += q0s[j * 8 + 6] * (ka * t1.z - kb * t1.w) +
           q0s[j * 8 + 7] * (kb * t1.z + ka * t1.w);
  }
  // reduce over the 8-lane group (butterfly: all lanes get the total)
  dot += __shfl_xor(dot, 1);
  dot += __shfl_xor(dot, 2);
  dot += __shfl_xor(dot, 4);
  dot *= 0.125f;  // 1/sqrt(64)
  if (mask[b * S_ + s] == 0) dot = -1e9f;
  if (j == 0) scores[(size_t)bh * S_ + s] = dot;

  // block max over the 32 s (duplicates across the 8-lane groups are fine)
  float mx = dot;
#pragma unroll
  for (int off = 8; off < 64; off <<= 1) mx = fmaxf(mx, __shfl_xor(mx, off));
  if ((tid & 63) == 0) wredm[tid >> 6] = mx;
  __syncthreads();
  mx = fmaxf(fmaxf(wredm[0], wredm[1]), fmaxf(wredm[2], wredm[3]));

  // block sum of exp(dot-mx); only group-lead contributes
  float e = (j == 0) ? expf(dot - mx) : 0.f;
#pragma unroll
  for (int off = 1; off < 64; off <<= 1) e += __shfl_xor(e, off);
  if ((tid & 63) == 0) wreds[tid >> 6] = e;
  __syncthreads();
  if (tid == 0) {
    mS[(size_t)(bh * 32 + chunk) * 2 + 0] = mx;
    mS[(size_t)(bh * 32 + chunk) * 2 + 1] =
        wreds[0] + wreds[1] + wreds[2] + wreds[3];
  }
}

// ---------------------------------------------------------------------------
// Conv1d (NCH, I=16, O=1024, k=3, pad=1) + bias + ReLU. Softmax combine is
// fused into the prologue (per-bh max + 1/sum from the 32 chunk partials);
// scores normalized on the fly. grid (S/16, B, 4 o-quarters).
// ---------------------------------------------------------------------------
__global__ __launch_bounds__(256) void conv_norm_relu_kernel(
    const float* __restrict__ scores, const float* __restrict__ mS,
    const float* __restrict__ cw, const float* __restrict__ cb,
    float* __restrict__ out) {
  const int b = blockIdx.y;
  const int s0 = blockIdx.x * 16;
  const int oz = blockIdx.z * 256;
  const int tid = threadIdx.x;

  __shared__ float msh[16], ish[16];
  __shared__ float sm[16][18];  // normalized p, [c][s0-1 .. s0+16]

  if (tid < 16) {
    const int bh = b * H_ + tid;
    float m = -3e38f;
#pragma unroll
    for (int c = 0; c < 32; ++c)
      m = fmaxf(m, mS[(size_t)(bh * 32 + c) * 2]);
    float S = 0.f;
#pragma unroll
    for (int c = 0; c < 32; ++c)
      S += mS[(size_t)(bh * 32 + c) * 2 + 1] *
           expf(mS[(size_t)(bh * 32 + c) * 2] - m);
    msh[tid] = m;
    ish[tid] = 1.f / S;
  }
  __syncthreads();

  for (int i = tid; i < 16 * 18; i += 256) {
    const int c = i / 18, ss = i % 18;
    const int gs = s0 - 1 + ss;
    float p = 0.f;
    if (gs >= 0 && gs < S_) {
      const int bh = b * H_ + c;
      p = expf(scores[(size_t)bh * S_ + gs] - msh[c]) * ish[c];
    }
    sm[c][ss] = p;
  }
  __syncthreads();

  const int og = tid >> 4;  // 0..15
  const int si = tid & 15;  // 0..15

  float r[16][3];
#pragma unroll
  for (int c = 0; c < 16; ++c) {
    r[c][0] = sm[c][si + 0];
    r[c][1] = sm[c][si + 1];
    r[c][2] = sm[c][si + 2];
  }

#pragma unroll 1
  for (int i = 0; i < 16; ++i) {
    const int o = oz + i * 16 + og;
    const float4* wo = (const float4*)(cw + (size_t)o * 48);
    float accv = cb[o];
#pragma unroll
    for (int q = 0; q < 12; ++q) {
      const float4 w4 = wo[q];
      const int f0 = q * 4;
      accv = fmaf(r[(f0 + 0) / 3][(f0 + 0) % 3], w4.x, accv);
      accv = fmaf(r[(f0 + 1) / 3][(f0 + 1) % 3], w4.y, accv);
      accv = fmaf(r[(f0 + 2) / 3][(f0 + 2) % 3], w4.z, accv);
      accv = fmaf(r[(f0 + 3) / 3][(f0 + 3) % 3], w4.w, accv);
    }
    out[((size_t)b * D_ + o) * S_ + s0 + si] = fmaxf(accv, 0.f);
  }
}

// ---------------------------------------------------------------------------
// Workspace (peak ~29.1 MB, well under the proven 36.4 MB):
//  [ 0, 8M)          Xbf  bf16
//  [ 8,16M)          G    bf16   (GEMM1 out, GEMM2 in, q0 in)
//  [16,24M)          Kbf  bf16   (GEMM2 out)
//  [24,26M)          WGT  bf16   [n][k]
//  [26,28M)          WkT  bf16   [n][k]
//  [28M, +512K)      part fp32 (q0 split-K partials)
//  [+512K, +768K)    ropeT
//  [+768K, +1024K)   scores fp32
//  [+1024K, +1040K)  mS (64*32*2 fp32)
// ---------------------------------------------------------------------------
extern "C" void kernel_launch(void* const* d_in, const int* in_sizes, int n_in,
                              void* d_out, int out_size, void* d_ws,
                              size_t ws_size, hipStream_t stream) {
  const float* x    = (const float*)d_in[0];
  const int*   mask = (const int*)d_in[1];
  const float* W_G  = (const float*)d_in[2];
  const float* b_G  = (const float*)d_in[3];
  const float* Wq   = (const float*)d_in[4];
  const float* bq   = (const float*)d_in[5];
  const float* Wk   = (const float*)d_in[6];
  const float* bk   = (const float*)d_in[7];
  const float* cw   = (const float*)d_in[8];
  const float* cb   = (const float*)d_in[9];
  float* out = (float*)d_out;

  char* ws = (char*)d_ws;
  unsigned short* Xbf = (unsigned short*)(ws);
  unsigned short* G   = (unsigned short*)(ws + (8u << 20));
  unsigned short* Kbf = (unsigned short*)(ws + (16u << 20));
  unsigned short* WGT = (unsigned short*)(ws + (24u << 20));
  unsigned short* WkT = (unsigned short*)(ws + (26u << 20));
  float* part   = (float*)(ws + (28u << 20));
  float* ropeT  = (float*)(ws + (28u << 20) + (512u << 10));
  float* scores = (float*)(ws + (28u << 20) + (768u << 10));
  float* mS     = (float*)(ws + (28u << 20) + (1024u << 10));

  prep_kernel<<<4224, 256, 0, stream>>>(x, W_G, Wk, Xbf, WGT, WkT, ropeT);
  gemm_bf16<<<512, 256, 0, stream>>>(Xbf, WGT, b_G, G, nullptr, nullptr, 512);
  gemm_bf16<<<640, 256, 0, stream>>>(G, WkT, bk, Kbf, Wq, part, 512);
  attn_scores_kernel<<<2048, 256, 0, stream>>>(Kbf, part, bq, ropeT, mask,
                                               scores, mS);
  conv_norm_relu_kernel<<<dim3(S_ / 16, B_, 4), 256, 0, stream>>>(
      scores, mS, cw, cb, out);
}